// Round 1
// 464.617 us; speedup vs baseline: 1.0405x; 1.0405x over previous
//
#include <hip/hip_runtime.h>

typedef _Float16 f16;
typedef __attribute__((ext_vector_type(4))) _Float16 f16x4;
typedef __attribute__((ext_vector_type(8))) _Float16 f16x8;
typedef __attribute__((ext_vector_type(4))) float f32x4;

#define BB 8
#define SS 1024
#define DD 1024
#define HH 16
#define HD 64
#define QPB 16
#define PROW 1040   // Pf row len (f16): 2080 B rows (16B-aligned); cols 0..1023 + 8-pad
#define TSTR 520    // T/W row stride (f16): 1040 B = 65*16 (16B-aligned rows)
#define KSTR 72     // prep-kernel LDS staging stride
#define RVSTR 520   // Rvt global row stride (f16)

#define VT_ELEMS  ((size_t)BB * HH * HD * SS)   // 8,388,608
#define RVT_ELEMS ((size_t)HD * RVSTR)          // 33,280
#define RKT_ELEMS ((size_t)513 * HD)            // 32,832
#define KT_ELEMS  ((size_t)BB * HH * SS * HD)   // 8,388,608
#define WS_PART ((VT_ELEMS + RVT_ELEMS + RKT_ELEMS) * 2)
#define WS_FULL ((VT_ELEMS + RVT_ELEMS + RKT_ELEMS + KT_ELEMS) * 2)

__device__ inline f16x8 cvt16(float4 a, float4 b) {
  f16x8 h;
  h[0] = (f16)a.x; h[1] = (f16)a.y; h[2] = (f16)a.z; h[3] = (f16)a.w;
  h[4] = (f16)b.x; h[5] = (f16)b.y; h[6] = (f16)b.z; h[7] = (f16)b.w;
  return h;
}

// ---- prep: Vt[b][h][d][s], Rvt[d][dist] (transposes), Kt[b][h][s][d], Rkt f16 casts ----
__global__ __launch_bounds__(256, 2)
void prep_kernel(const float* __restrict__ Vg, const float* __restrict__ Rvg,
                 const float* __restrict__ Kg, const float* __restrict__ Rkg,
                 f16* __restrict__ Vt, f16* __restrict__ Rvt,
                 f16* __restrict__ Rkt, f16* __restrict__ Kt) {
  __shared__ __align__(16) f16 Tt[64 * KSTR];
  const int tid = threadIdx.x;
  const int bid = blockIdx.x;

  if (bid < 2056) {  // transpose sections (V, Rv)
    const int sr = tid >> 2, cs = (tid & 3) * 16;
    const float* src;
    int srcstride;
    f16* dst;
    int dststride, dstcol;
    if (bid < 2048) {
      int b = bid >> 8, h = (bid >> 4) & 15, tc = bid & 15;
      src = Vg + ((size_t)(b * SS + tc * 64)) * DD + h * HD;
      srcstride = DD;
      dst = Vt + ((size_t)((b * HH + h) * HD)) * SS;
      dststride = SS; dstcol = tc * 64;
    } else {
      int cc = bid - 2048;                       // 0..7, dists 0..511
      src = Rvg + ((size_t)(cc * 64)) * HD;
      srcstride = HD;
      dst = Rvt;
      dststride = RVSTR; dstcol = cc * 64;
    }
    {
      const float* s = src + (size_t)sr * srcstride + cs;
      float4 v0 = *(const float4*)(s);
      float4 v1 = *(const float4*)(s + 4);
      float4 v2 = *(const float4*)(s + 8);
      float4 v3 = *(const float4*)(s + 12);
      *(f16x8*)(Tt + sr * KSTR + cs) = cvt16(v0, v1);
      *(f16x8*)(Tt + sr * KSTR + cs + 8) = cvt16(v2, v3);
    }
    __syncthreads();
    {
      f16x8 o0, o1;
      #pragma unroll
      for (int i = 0; i < 8; ++i) o0[i] = Tt[(cs + i) * KSTR + sr];
      #pragma unroll
      for (int i = 0; i < 8; ++i) o1[i] = Tt[(cs + 8 + i) * KSTR + sr];
      f16* o = dst + (size_t)sr * dststride + dstcol + cs;
      *(f16x8*)(o) = o0;
      *(f16x8*)(o + 8) = o1;
    }
  } else if (bid < 2058) {  // Rk cast: 513*64 = 32832 elems, 2 blocks
    const int base = (bid - 2056) * 16416;
    for (int j = tid; j < 16416; j += 256)
      Rkt[base + j] = (f16)Rkg[base + j];
  } else {
    // K cast -> Kt[b][h][s][d]: 2048 blocks x 4 iters x 256 thr = 2,097,152 float4
    const int n = bid - 2058;
    #pragma unroll
    for (int jj = 0; jj < 4; ++jj) {
      int o4 = n * 1024 + jj * 256 + tid;
      int d4 = o4 & 15;
      int s  = (o4 >> 4) & 1023;
      int bh = o4 >> 14;                 // 0..127
      int b = bh >> 4, h = bh & 15;
      float4 v = *(const float4*)(Kg + ((size_t)(b * SS + s)) * DD + h * HD + d4 * 4);
      f16x4 hv; hv[0] = (f16)v.x; hv[1] = (f16)v.y; hv[2] = (f16)v.z; hv[3] = (f16)v.w;
      *(f16x4*)(Kt + (size_t)o4 * 4) = hv;
    }
  }
}

// ---- main v6: 512-thread / 8-wave blocks, SAME 50 KB LDS -> 3 blocks/CU = 24 waves/CU
// (was 12). Wave pairs (w, w+4) split the k range (Phase A/B) and dist range (T/Wrelv);
// partial co accumulators reduced through Pf (dead after Phase W). Serial phase depth
// halves everywhere: A 16->8, B 16->8, T 8->4, W 4->2, Wrelv 8->4 iters.
template <bool KT16>
__global__ __launch_bounds__(512, 6)
void circ_attn_v6(const float* __restrict__ Qg, const float* __restrict__ Kg,
                  const f16* __restrict__ Kt, const f16* __restrict__ Rkt,
                  const float* __restrict__ Rkg, const float* __restrict__ Rvg,
                  const f16* __restrict__ Vt, const f16* __restrict__ Rvt,
                  float* __restrict__ Out) {
  __shared__ __align__(16) f16 Pf[QPB * PROW];
  __shared__ __align__(16) f16 Tb[QPB * TSTR];   // bias table T, later reused as W
  __shared__ float lsw[8][16];
  __shared__ float w512[16];

  // XCD swizzle: all 64 q-blocks of one (b,h) land on XCD (g & 7)
  const int i = blockIdx.x;
  const int g = ((i >> 9) << 3) | (i & 7);   // (b,h) group 0..127
  const int m = (i >> 3) & 63;               // q-block 0..63
  const int b = g >> 4;
  const int h = g & 15;
  const int q0 = m * QPB;

  const int tid = threadIdx.x;
  const int w = tid >> 6;        // 0..7
  const int lane = tid & 63;
  const int quad = lane >> 4;
  const int l16 = lane & 15;
  const int wd = w & 3;          // output d-group 0..3
  const int wh = w >> 2;         // k-half / dist-half 0..1

  // ---- Q fragments straight from global (A-layout == B-layout; same for all waves) ----
  f16x8 qf0, qf1;
  {
    const float* qrow = Qg + ((size_t)(b * SS + q0 + l16)) * DD + h * HD;
    float4 a0 = *(const float4*)(qrow + quad * 8);
    float4 a1 = *(const float4*)(qrow + quad * 8 + 4);
    float4 a2 = *(const float4*)(qrow + 32 + quad * 8);
    float4 a3 = *(const float4*)(qrow + 32 + quad * 8 + 4);
    qf0 = cvt16(a0, a1);
    qf1 = cvt16(a2, a3);
  }

  // ---- Phase T: T[q][dist] = Q . Rk^T; wave w covers dists cc*128 + w*16 + l16 ----
  {
    const f16* rkp = Rkt + ((size_t)(w * 16 + l16)) * HD + quad * 8;
    f16x8 t0 = *(const f16x8*)(rkp);
    f16x8 t1 = *(const f16x8*)(rkp + 32);
    #pragma unroll
    for (int cc = 0; cc < 4; ++cc) {
      f16x8 c0 = t0, c1 = t1;
      if (cc < 3) {
        const f16* np = rkp + (size_t)(cc + 1) * 128 * HD;
        t0 = *(const f16x8*)(np);
        t1 = *(const f16x8*)(np + 32);
      }
      f32x4 c = {0.f, 0.f, 0.f, 0.f};
      c = __builtin_amdgcn_mfma_f32_16x16x32_f16(qf0, c0, c, 0, 0, 0);
      c = __builtin_amdgcn_mfma_f32_16x16x32_f16(qf1, c1, c, 0, 0, 0);
      const int dbase = cc * 128 + w * 16 + l16;
      #pragma unroll
      for (int r = 0; r < 4; ++r)
        Tb[(quad * 4 + r) * TSTR + dbase] = (f16)c[r];
    }
  }
  // dist 512 (wave 0 only, f32 path)
  if (w == 0) {
    const float* rk = Rkg + 512 * HD;
    float t = 0.f;
    #pragma unroll
    for (int j = 0; j < 8; ++j) t += (float)qf0[j] * rk[quad * 8 + j];
    #pragma unroll
    for (int j = 0; j < 8; ++j) t += (float)qf1[j] * rk[32 + quad * 8 + j];
    t += __shfl_xor(t, 16);
    t += __shfl_xor(t, 32);
    if (quad == 0) Tb[l16 * TSTR + 512] = (f16)t;
  }

  // Phase A initial K prefetch (issued before barrier; independent of Tb)
  const f16* kp16 = KT16 ?
      (Kt + (((size_t)(b * HH + h) << 10) + w * 16 + l16) * HD + quad * 8) : nullptr;
  const float* kp32 = KT16 ? nullptr :
      (Kg + ((size_t)(b * SS + w * 16 + l16)) * DD + h * HD + quad * 8);
  f16x8 ka0, ka1, kb0, kb1;
  float4 f0, f1, f2, f3;
  if (KT16) {
    ka0 = *(const f16x8*)(kp16);
    ka1 = *(const f16x8*)(kp16 + 32);
    kb0 = *(const f16x8*)(kp16 + 128 * HD);
    kb1 = *(const f16x8*)(kp16 + 128 * HD + 32);
  } else {
    f0 = *(const float4*)(kp32);
    f1 = *(const float4*)(kp32 + 4);
    f2 = *(const float4*)(kp32 + 32);
    f3 = *(const float4*)(kp32 + 36);
  }
  __syncthreads();   // barrier 1: Tb(T) ready

  // ---- Phase A: S^T = K . Q^T ; wave w covers k = kc*128 + w*16 + .. (8 iters) ----
  {
    float psum = 0.f;
    #pragma unroll 2
    for (int kc = 0; kc < 8; ++kc) {
      f16x8 c0, c1;
      if (KT16) {
        c0 = ka0; c1 = ka1; ka0 = kb0; ka1 = kb1;
        if (kc < 6) {
          const f16* np = kp16 + (size_t)(kc + 2) * 128 * HD;
          kb0 = *(const f16x8*)(np);
          kb1 = *(const f16x8*)(np + 32);
        }
      } else {
        c0 = cvt16(f0, f1); c1 = cvt16(f2, f3);
        if (kc < 7) {
          const float* s = kp32 + (size_t)(kc + 1) * 128 * DD;
          f0 = *(const float4*)(s);      f1 = *(const float4*)(s + 4);
          f2 = *(const float4*)(s + 32); f3 = *(const float4*)(s + 36);
        }
      }
      // bias gathers (independent of MFMA result -> issued early)
      const int kb_ = kc * 128 + w * 16 + quad * 4;
      const int q = q0 + l16;
      const int j0 = (q - kb_) & 1023;
      float tv[4];
      #pragma unroll
      for (int r = 0; r < 4; ++r) {
        int jr = (j0 - r) & 1023;
        int dist = (jr < 1024 - jr) ? jr : 1024 - jr;
        tv[r] = (float)Tb[l16 * TSTR + dist];
      }
      f32x4 c = {0.f, 0.f, 0.f, 0.f};
      c = __builtin_amdgcn_mfma_f32_16x16x32_f16(c0, qf0, c, 0, 0, 0);
      c = __builtin_amdgcn_mfma_f32_16x16x32_f16(c1, qf1, c, 0, 0, 0);
      f16x4 pv;
      #pragma unroll
      for (int r = 0; r < 4; ++r) {
        float s = fmaf(c[r], 0.125f, tv[r]);
        float p = __expf(s);            // no max-subtract: |s| small, fp32-safe
        pv[r] = (f16)p;
        psum += p;
      }
      *(f16x4*)(Pf + l16 * PROW + kb_) = pv;
    }
    psum += __shfl_xor(psum, 16);
    psum += __shfl_xor(psum, 32);
    if (quad == 0) lsw[w][l16] = psum;
  }
  // circular pad: Pf[q][1024..1031] = Pf[q][0..7] (wave 0 wrote cols 0..7 at kc=0)
  if (w == 0 && lane < 16)
    *(f16x8*)(Pf + lane * PROW + 1024) = *(const f16x8*)(Pf + lane * PROW);

  // Phase B initial V prefetch (independent of Pf); wave w: d-group wd, k-half wh
  const f16* vtp = Vt + ((size_t)((b * HH + h) * HD) + wd * 16 + l16) * SS
                      + wh * 512 + quad * 8;
  f16x8 va0 = *(const f16x8*)(vtp);
  f16x8 va1 = *(const f16x8*)(vtp + 32);
  f16x8 vb0 = *(const f16x8*)(vtp + 64);
  f16x8 vb1 = *(const f16x8*)(vtp + 96);
  __syncthreads();   // barrier 2: Pf + pad + lsw ready

  // ---- Phase B: co_partial = P[., k-half] . V[k-half, d-group]  (8 iters) ----
  f32x4 co = {0.f, 0.f, 0.f, 0.f};
  {
    #pragma unroll 2
    for (int kc = 0; kc < 8; ++kc) {
      f16x8 cb0 = va0, cb1 = va1;
      va0 = vb0; va1 = vb1;
      if (kc < 6) {
        const f16* s = vtp + (kc + 2) * 64;
        vb0 = *(const f16x8*)(s);
        vb1 = *(const f16x8*)(s + 32);
      }
      f16x8 ap0 = *(const f16x8*)(Pf + l16 * PROW + wh * 512 + kc * 64 + quad * 8);
      f16x8 ap1 = *(const f16x8*)(Pf + l16 * PROW + wh * 512 + kc * 64 + 32 + quad * 8);
      co = __builtin_amdgcn_mfma_f32_16x16x32_f16(ap0, cb0, co, 0, 0, 0);
      co = __builtin_amdgcn_mfma_f32_16x16x32_f16(ap1, cb1, co, 0, 0, 0);
    }
  }

  // ---- Phase W (vectorized): 1024 (row, 8-dist-group) tasks over 512 threads ----
  #pragma unroll
  for (int it = 0; it < 2; ++it) {
    const int flat = it * 512 + tid;   // whole wave shares one row ql
    const int ql = flat >> 6;
    const int gg = flat & 63;          // dist group: dists gg*8 .. gg*8+7
    const int qq = q0 + ql;
    const int bm = (qq - 8 * gg - 7) & 1023;
    const int bp = (qq + 8 * gg) & 1023;
    const f16* rowp = Pf + ql * PROW;
    f16 mv[8], pv2[8];
    #pragma unroll
    for (int j = 0; j < 8; ++j) mv[j] = rowp[bm + j];
    #pragma unroll
    for (int j = 0; j < 8; ++j) pv2[j] = rowp[bp + j];
    f16x8 wv;
    #pragma unroll
    for (int j = 0; j < 8; ++j) wv[j] = (f16)((float)mv[7 - j] + (float)pv2[j]);
    if (gg == 0) wv[0] = mv[7];        // dist 0: single term P[q]
    *(f16x8*)(Tb + ql * TSTR + gg * 8) = wv;
  }
  if (tid < 16)                        // dist 512: single term P[(q+512) mod S]
    w512[tid] = (float)Pf[tid * PROW + ((q0 + tid + 512) & 1023)];

  // Wrelv initial Rv prefetch (independent of W); wave w: d-group wd, dist-half wh
  const f16* rvp = Rvt + ((size_t)(wd * 16 + l16)) * RVSTR + wh * 256 + quad * 8;
  f16x8 r0 = *(const f16x8*)(rvp);
  f16x8 r1 = *(const f16x8*)(rvp + 32);
  __syncthreads();   // barrier 3: W ready

  // ---- Phase Wrelv: co_partial += W[., dist-half] . Rv[dist-half, d-group] (4 iters) ----
  {
    #pragma unroll
    for (int cc = 0; cc < 4; ++cc) {
      f16x8 cb0 = r0, cb1 = r1;
      if (cc < 3) {
        const f16* s = rvp + (cc + 1) * 64;
        r0 = *(const f16x8*)(s);
        r1 = *(const f16x8*)(s + 32);
      }
      f16x8 aw0 = *(const f16x8*)(Tb + l16 * TSTR + wh * 256 + cc * 64 + quad * 8);
      f16x8 aw1 = *(const f16x8*)(Tb + l16 * TSTR + wh * 256 + cc * 64 + 32 + quad * 8);
      co = __builtin_amdgcn_mfma_f32_16x16x32_f16(aw0, cb0, co, 0, 0, 0);
      co = __builtin_amdgcn_mfma_f32_16x16x32_f16(aw1, cb1, co, 0, 0, 0);
    }
  }

  // ---- pairwise partial-sum reduction through Pf (dead after Phase W) ----
  if (w >= 4)
    *(f32x4*)((float*)Pf + ((size_t)(wd * 64 + lane)) * 4) = co;
  __syncthreads();   // barrier 4: partials staged
  if (w < 4) {
    f32x4 part = *(const f32x4*)((const float*)Pf + ((size_t)(w * 64 + lane)) * 4);
    co += part;
    // ---- finalize: dist-512 rel_v term + normalize + store ----
    const int d = w * 16 + l16;
    const float rv512 = Rvg[512 * HD + d];
    #pragma unroll
    for (int r = 0; r < 4; ++r) {
      int ql = quad * 4 + r;
      float l = 0.f;
      #pragma unroll
      for (int j = 0; j < 8; ++j) l += lsw[j][ql];
      float o = co[r] + w512[ql] * rv512;
      Out[((size_t)(b * SS + q0 + ql)) * DD + h * HD + d] = o / l;
    }
  }
}

// ---- fallback (R2-style, used only if ws_size is tiny) ----
#define FPSTR 1032
#define FVSTR 68
__global__ __launch_bounds__(256, 2)
void circ_attn_mfma(const float* __restrict__ Qg, const float* __restrict__ Kg,
                    const float* __restrict__ Vg, const float* __restrict__ Rkg,
                    const float* __restrict__ Rvg, float* __restrict__ Out) {
  __shared__ __align__(16) f16 Pf[QPB * FPSTR];
  __shared__ __align__(16) f16 Tb[QPB * TSTR];
  __shared__ __align__(16) f16 Sb[64 * KSTR];
  __shared__ __align__(16) f16 Qb[QPB * KSTR];
  __shared__ float lsw[4][16];
  const int bid = blockIdx.x;
  const int b = bid >> 10, h = (bid >> 6) & 15, q0 = (bid & 63) * QPB;
  const int tid = threadIdx.x, w = tid >> 6, lane = tid & 63;
  const int quad = lane >> 4, l16 = lane & 15;
  auto stage64 = [&](const float* src, int rstride, f16* dst, int dstr) {
    #pragma unroll
    for (int jj = 0; jj < 4; ++jj) {
      int i = jj * 256 + tid;
      int r = i >> 4, c = (i & 15) << 2;
      float4 v = *(const float4*)(src + (size_t)r * rstride + c);
      f16x4 hv; hv[0] = (f16)v.x; hv[1] = (f16)v.y; hv[2] = (f16)v.z; hv[3] = (f16)v.w;
      *(f16x4*)(dst + r * dstr + c) = hv;
    }
  };
  {
    int r = tid >> 4, c = (tid & 15) << 2;
    float4 v = *(const float4*)(Qg + (size_t)(b * SS + q0 + r) * DD + h * HD + c);
    f16x4 hv; hv[0] = (f16)v.x; hv[1] = (f16)v.y; hv[2] = (f16)v.z; hv[3] = (f16)v.w;
    *(f16x4*)(Qb + r * KSTR + c) = hv;
  }
  __syncthreads();
  const f16x8 qf0 = *(const f16x8*)(Qb + l16 * KSTR + quad * 8);
  const f16x8 qf1 = *(const f16x8*)(Qb + l16 * KSTR + 32 + quad * 8);
  #pragma unroll 1
  for (int cc = 0; cc < 8; ++cc) {
    stage64(Rkg + (size_t)(cc * 64) * HD, HD, Sb, KSTR);
    __syncthreads();
    f16x8 rk0 = *(const f16x8*)(Sb + (w * 16 + l16) * KSTR + quad * 8);
    f16x8 rk1 = *(const f16x8*)(Sb + (w * 16 + l16) * KSTR + 32 + quad * 8);
    f32x4 c = {0.f, 0.f, 0.f, 0.f};
    c = __builtin_amdgcn_mfma_f32_16x16x32_f16(qf0, rk0, c, 0, 0, 0);
    c = __builtin_amdgcn_mfma_f32_16x16x32_f16(qf1, rk1, c, 0, 0, 0);
    const int dbase = cc * 64 + w * 16 + l16;
    #pragma unroll
    for (int r = 0; r < 4; ++r) Tb[(quad * 4 + r) * TSTR + dbase] = (f16)c[r];
    __syncthreads();
  }
  if (w == 0) {
    float t = 0.f;
    #pragma unroll
    for (int i = 0; i < 16; ++i)
      t += (float)Qb[l16 * KSTR + quad * 16 + i] * Rkg[512 * HD + quad * 16 + i];
    t += __shfl_xor(t, 16); t += __shfl_xor(t, 32);
    if (quad == 0) Tb[l16 * TSTR + 512] = (f16)t;
  }
  float psum = 0.f;
  #pragma unroll 1
  for (int kc = 0; kc < 16; ++kc) {
    stage64(Kg + (size_t)(b * SS + kc * 64) * DD + h * HD, DD, Sb, KSTR);
    __syncthreads();
    f16x8 ka0 = *(const f16x8*)(Sb + (w * 16 + l16) * KSTR + quad * 8);
    f16x8 ka1 = *(const f16x8*)(Sb + (w * 16 + l16) * KSTR + 32 + quad * 8);
    f32x4 c = {0.f, 0.f, 0.f, 0.f};
    c = __builtin_amdgcn_mfma_f32_16x16x32_f16(ka0, qf0, c, 0, 0, 0);
    c = __builtin_amdgcn_mfma_f32_16x16x32_f16(ka1, qf1, c, 0, 0, 0);
    const int kb = kc * 64 + w * 16 + quad * 4;
    const int q = q0 + l16;
    f16x4 pv;
    #pragma unroll
    for (int r = 0; r < 4; ++r) {
      int key = kb + r;
      int j = (q - key) & 1023;
      int dist = (j < 1024 - j) ? j : 1024 - j;
      float s = c[r] * 0.125f + (float)Tb[l16 * TSTR + dist];
      float p = __expf(s);
      pv[r] = (f16)p;
      psum += p;
    }
    *(f16x4*)(Pf + l16 * FPSTR + kb) = pv;
    __syncthreads();
  }
  psum += __shfl_xor(psum, 16); psum += __shfl_xor(psum, 32);
  if (quad == 0) lsw[w][l16] = psum;
  f32x4 co = {0.f, 0.f, 0.f, 0.f};
  const int d = w * 16 + l16;
  #pragma unroll 1
  for (int kc = 0; kc < 16; ++kc) {
    stage64(Vg + (size_t)(b * SS + kc * 64) * DD + h * HD, DD, Sb, FVSTR);
    __syncthreads();
    #pragma unroll
    for (int kd = 0; kd < 2; ++kd) {
      f16x8 bv;
      #pragma unroll
      for (int j = 0; j < 8; ++j) bv[j] = Sb[(kd * 32 + quad * 8 + j) * FVSTR + d];
      f16x8 ap = *(const f16x8*)(Pf + l16 * FPSTR + kc * 64 + kd * 32 + quad * 8);
      co = __builtin_amdgcn_mfma_f32_16x16x32_f16(ap, bv, co, 0, 0, 0);
    }
    __syncthreads();
  }
  #pragma unroll 1
  for (int i = tid; i < QPB * 513; i += 256) {
    int ql = i / 513, dist = i - ql * 513, q = q0 + ql;
    int k1 = (q - dist) & 1023;
    float wv = (float)Pf[ql * FPSTR + k1];
    if (dist != 0 && dist != 512) wv += (float)Pf[ql * FPSTR + ((q + dist) & 1023)];
    Tb[ql * TSTR + dist] = (f16)wv;
  }
  __syncthreads();
  #pragma unroll 1
  for (int cc = 0; cc < 8; ++cc) {
    stage64(Rvg + (size_t)(cc * 64) * HD, HD, Sb, FVSTR);
    __syncthreads();
    #pragma unroll
    for (int kd = 0; kd < 2; ++kd) {
      f16x8 bv;
      #pragma unroll
      for (int j = 0; j < 8; ++j) bv[j] = Sb[(kd * 32 + quad * 8 + j) * FVSTR + d];
      f16x8 aw = *(const f16x8*)(Tb + l16 * TSTR + cc * 64 + kd * 32 + quad * 8);
      co = __builtin_amdgcn_mfma_f32_16x16x32_f16(aw, bv, co, 0, 0, 0);
    }
    __syncthreads();
  }
  const float rv512 = Rvg[512 * HD + d];
  #pragma unroll
  for (int r = 0; r < 4; ++r) {
    int ql = quad * 4 + r;
    float l = lsw[0][ql] + lsw[1][ql] + lsw[2][ql] + lsw[3][ql];
    float o = co[r] + (float)Tb[ql * TSTR + 512] * rv512;
    Out[(size_t)(b * SS + q0 + ql) * DD + h * HD + d] = o / l;
  }
}

extern "C" void kernel_launch(void* const* d_in, const int* in_sizes, int n_in,
                              void* d_out, int out_size, void* d_ws, size_t ws_size,
                              hipStream_t stream) {
  const float* q  = (const float*)d_in[0];
  const float* k  = (const float*)d_in[1];
  const float* v  = (const float*)d_in[2];
  const float* rk = (const float*)d_in[3];
  const float* rv = (const float*)d_in[4];
  float* out = (float*)d_out;
  const int nblocks = BB * HH * (SS / QPB);  // 8192
  f16* vt  = (f16*)d_ws;
  f16* rvt = vt + VT_ELEMS;
  f16* rkt = rvt + RVT_ELEMS;
  f16* kt  = rkt + RKT_ELEMS;
  if (ws_size >= WS_FULL) {
    prep_kernel<<<dim3(2058 + 2048), dim3(256), 0, stream>>>(v, rv, k, rk, vt, rvt, rkt, kt);
    circ_attn_v6<true><<<dim3(nblocks), dim3(512), 0, stream>>>(
        q, k, kt, rkt, rk, rv, vt, rvt, out);
  } else if (ws_size >= WS_PART) {
    prep_kernel<<<dim3(2058), dim3(256), 0, stream>>>(v, rv, k, rk, vt, rvt, rkt, kt);
    circ_attn_v6<false><<<dim3(nblocks), dim3(512), 0, stream>>>(
        q, k, kt, rkt, rk, rv, vt, rvt, out);
  } else {
    circ_attn_mfma<<<dim3(nblocks), dim3(256), 0, stream>>>(q, k, v, rk, rv, out);
  }
}